// Round 2
// baseline (1072.346 us; speedup 1.0000x reference)
//
#include <hip/hip_runtime.h>

#define N 4096
#define IN_DIM 256
#define HID 64
#define NHEADS 4
#define OUT_DIM 128
#define JSPLIT 16
#define CHUNK (N / JSPLIT) /* 256 */

// ---------------------------------------------------------------------------
// gemm1: x[N,256] @ W_heads[4][256][64] -> Wh1[4][N][64]
// ---------------------------------------------------------------------------
__global__ void gemm1_kernel(const float* __restrict__ x,
                             const float* __restrict__ W,
                             float* __restrict__ Wh) {
    __shared__ float xs[8 * IN_DIM];
    const int t = threadIdx.x;
    const int c = t & 63, h = t >> 6;
    const int i0 = blockIdx.x * 8;
    const float4* xg = (const float4*)(x + (size_t)i0 * IN_DIM);
    float4* xs4 = (float4*)xs;
    for (int u = t; u < 8 * IN_DIM / 4; u += 256) xs4[u] = xg[u];
    __syncthreads();
    float acc[8];
#pragma unroll
    for (int r = 0; r < 8; r++) acc[r] = 0.f;
    const float* Wp = W + (size_t)h * IN_DIM * HID + c;
    for (int k = 0; k < IN_DIM; k += 4) {
        const float w0 = Wp[(size_t)(k + 0) * HID];
        const float w1 = Wp[(size_t)(k + 1) * HID];
        const float w2 = Wp[(size_t)(k + 2) * HID];
        const float w3 = Wp[(size_t)(k + 3) * HID];
#pragma unroll
        for (int r = 0; r < 8; r++) {
            const float4 xv = *(const float4*)(xs + r * IN_DIM + k);
            acc[r] += xv.x * w0 + xv.y * w1 + xv.z * w2 + xv.w * w3;
        }
    }
#pragma unroll
    for (int r = 0; r < 8; r++)
        Wh[((size_t)h * N + (i0 + r)) * HID + c] = acc[r];
}

// ---------------------------------------------------------------------------
// fkern1: f1[h][i] = sum_c Wh[h][i][c]*a[h][c]; f2 with a[h][64+c]
// ---------------------------------------------------------------------------
__global__ void fkern1(const float* __restrict__ Wh, const float* __restrict__ a,
                       float* __restrict__ f1, float* __restrict__ f2) {
    const int i = blockIdx.x;
    const int t = threadIdx.x;
    const int h = t >> 6, c = t & 63;
    const float v = Wh[((size_t)h * N + i) * HID + c];
    float v1 = v * a[h * 2 * HID + c];
    float v2 = v * a[h * 2 * HID + HID + c];
#pragma unroll
    for (int m = 32; m > 0; m >>= 1) {
        v1 += __shfl_xor(v1, m, 64);
        v2 += __shfl_xor(v2, m, 64);
    }
    if (c == 0) { f1[(size_t)h * N + i] = v1; f2[(size_t)h * N + i] = v2; }
}

// ---------------------------------------------------------------------------
// fkern2: f1b[i] = sum_c Wh2[i][c]*a_out[c]; f2b with a_out[128+c]
// ---------------------------------------------------------------------------
__global__ void fkern2(const float* __restrict__ Wh2, const float* __restrict__ a2,
                       float* __restrict__ f1, float* __restrict__ f2) {
    __shared__ float red[4];
    const int i = blockIdx.x, t = threadIdx.x;
    const float v = Wh2[(size_t)i * OUT_DIM + t];
    float v1 = v * a2[t];
    float v2 = v * a2[OUT_DIM + t];
#pragma unroll
    for (int m = 32; m > 0; m >>= 1) {
        v1 += __shfl_xor(v1, m, 64);
        v2 += __shfl_xor(v2, m, 64);
    }
    const int w = t >> 6;
    if ((t & 63) == 0) { red[w * 2] = v1; red[w * 2 + 1] = v2; }
    __syncthreads();
    if (t == 0) { f1[i] = red[0] + red[2]; f2[i] = red[1] + red[3]; }
}

// ---------------------------------------------------------------------------
// Fused single-pass masked-softmax aggregation.
// ROUND 2: acc shrunk to 16 floats/thread (64 B -> guaranteed SROA into
// VGPRs; the acc[64] version spilled to scratch: VGPR=56, VALUBusy=14%).
// Feature dim split across gridDim.z: thread owns (row i, 16 cols).
// p = exp(lrelu(f1+f2)) recomputed per column-group (cheap: ~3 us of exp).
// group = z*4+slot -> (head h, colslice cs). Channel index group*16+q
// matches the old [h*D + c] partial layout, so reduce_kernel is unchanged.
// ---------------------------------------------------------------------------
template <int NH, int D>
__global__ __launch_bounds__(256, 4) void attn_kernel(
        const int* __restrict__ adj, const float* __restrict__ Wh,
        const float* __restrict__ f1g, const float* __restrict__ f2g,
        float* __restrict__ partA, float* __restrict__ partS) {
    const int t = threadIdx.x;
    const int slot = t >> 6, r = t & 63;
    const int group = blockIdx.z * 4 + slot;   // [0, NH*D/16)
    const int h = group / (D / 16);
    const int cs = group % (D / 16);
    const int c0 = cs * 16;
    const int i = blockIdx.x * 64 + r;
    const int split = blockIdx.y;
    const int j0 = split * CHUNK;

    const float f1 = f1g[(size_t)h * N + i];
    const int* adjp = adj + (size_t)i * N + j0;
    const float* f2p = f2g + (size_t)h * N + j0;
    const float* whp = Wh + ((size_t)h * N + j0) * D + c0;

    float acc[16];
#pragma unroll
    for (int q = 0; q < 16; q++) acc[q] = 0.f;
    float s = 0.f;

    for (int jj = 0; jj < CHUNK; jj += 4) {
        const int4 a4 = *(const int4*)(adjp + jj);
        const float4 f4 = *(const float4*)(f2p + jj);
        const int am[4] = {a4.x, a4.y, a4.z, a4.w};
        const float fm[4] = {f4.x, f4.y, f4.z, f4.w};
#pragma unroll
        for (int u = 0; u < 4; u++) {
            float e = f1 + fm[u];
            e = fmaxf(e, 0.5f * e);              // LeakyReLU(0.5), monotone
            const float p = (am[u] > 0) ? __expf(e) : 0.f;
            s += p;
            const float4* wp = (const float4*)(whp + (size_t)(jj + u) * D);
            const float4 w0 = wp[0], w1 = wp[1], w2 = wp[2], w3 = wp[3];
            acc[0]  += p * w0.x; acc[1]  += p * w0.y;
            acc[2]  += p * w0.z; acc[3]  += p * w0.w;
            acc[4]  += p * w1.x; acc[5]  += p * w1.y;
            acc[6]  += p * w1.z; acc[7]  += p * w1.w;
            acc[8]  += p * w2.x; acc[9]  += p * w2.y;
            acc[10] += p * w2.z; acc[11] += p * w2.w;
            acc[12] += p * w3.x; acc[13] += p * w3.y;
            acc[14] += p * w3.z; acc[15] += p * w3.w;
        }
    }

    // partA[(split*(NH*D) + group*16 + q)][i]  (coalesced in i)
#pragma unroll
    for (int q = 0; q < 16; q++)
        partA[((size_t)split * (NH * D) + group * 16 + q) * N + i] = acc[q];
    if (cs == 0) partS[((size_t)split * NH + h) * N + i] = s;
}

// ---------------------------------------------------------------------------
// reduce: combine j-split partials, divide by softmax denom, apply ELU.
// ---------------------------------------------------------------------------
__global__ void reduce_kernel(const float* __restrict__ partA,
                              const float* __restrict__ partS,
                              float* __restrict__ outp, int OUTW, int NH,
                              int strideC, int strideI) {
    const int i = blockIdx.x * 256 + threadIdx.x;
    const int hc = blockIdx.y;
    const int hd = hc / (OUTW / NH);
    float a = 0.f, ss = 0.f;
    for (int sp = 0; sp < JSPLIT; sp++) {
        a  += partA[((size_t)sp * OUTW + hc) * N + i];
        ss += partS[((size_t)sp * NH + hd) * N + i];
    }
    float v = a / ss;
    v = (v > 0.f) ? v : (__expf(v) - 1.f);       // ELU
    outp[(size_t)hc * strideC + (size_t)i * strideI] = v;
}

// ---------------------------------------------------------------------------
// gemm2: h1T[256][N] (k-major) @ W_out[256][128] -> Wh2[N][128]
// ---------------------------------------------------------------------------
__global__ void gemm2_kernel(const float* __restrict__ h1T,
                             const float* __restrict__ W2,
                             float* __restrict__ Wh2) {
    __shared__ float hs[8 * IN_DIM];
    const int t = threadIdx.x;
    const int c = t & 127, rh = t >> 7;
    const int i0 = blockIdx.x * 8;
    for (int u = t; u < 8 * IN_DIM; u += 256) {
        const int r = u & 7, k = u >> 3;
        hs[r * IN_DIM + k] = h1T[(size_t)k * N + i0 + r];
    }
    __syncthreads();
    float acc[4];
#pragma unroll
    for (int rr = 0; rr < 4; rr++) acc[rr] = 0.f;
    for (int k = 0; k < IN_DIM; k += 4) {
        const float w0 = W2[(size_t)(k + 0) * OUT_DIM + c];
        const float w1 = W2[(size_t)(k + 1) * OUT_DIM + c];
        const float w2 = W2[(size_t)(k + 2) * OUT_DIM + c];
        const float w3 = W2[(size_t)(k + 3) * OUT_DIM + c];
#pragma unroll
        for (int rr = 0; rr < 4; rr++) {
            const float4 hv = *(const float4*)(hs + (rh * 4 + rr) * IN_DIM + k);
            acc[rr] += hv.x * w0 + hv.y * w1 + hv.z * w2 + hv.w * w3;
        }
    }
#pragma unroll
    for (int rr = 0; rr < 4; rr++)
        Wh2[(size_t)(i0 + rh * 4 + rr) * OUT_DIM + c] = acc[rr];
}

// ---------------------------------------------------------------------------
extern "C" void kernel_launch(void* const* d_in, const int* in_sizes, int n_in,
                              void* d_out, int out_size, void* d_ws, size_t ws_size,
                              hipStream_t stream) {
    const float* x   = (const float*)d_in[0];
    const int*   adj = (const int*)d_in[1];
    const float* Wh_ = (const float*)d_in[2];
    const float* ah  = (const float*)d_in[3];
    const float* W2  = (const float*)d_in[4];
    const float* a2  = (const float*)d_in[5];
    float* out = (float*)d_out;

    float* ws   = (float*)d_ws;
    float* Wh1  = ws;                                  // 4*N*64   = 1048576
    float* f1a  = Wh1 + (size_t)NHEADS * N * HID;      // 16384
    float* f2a  = f1a + (size_t)NHEADS * N;            // 16384
    float* h1T  = f2a + (size_t)NHEADS * N;            // 256*N    = 1048576
    float* Wh2v = h1T + (size_t)IN_DIM * N;            // N*128    = 524288
    float* f1b  = Wh2v + (size_t)N * OUT_DIM;          // 4096
    float* f2b  = f1b + N;                             // 4096
    float* partA = f2b + N;                            // 16*256*N = 16777216
    float* partS = partA + (size_t)JSPLIT * 256 * N;   // 16*4*N   = 262144

    // ---- layer 1 ----
    gemm1_kernel<<<N / 8, 256, 0, stream>>>(x, Wh_, Wh1);
    fkern1<<<N, 256, 0, stream>>>(Wh1, ah, f1a, f2a);
    attn_kernel<NHEADS, HID>
        <<<dim3(N / 64, JSPLIT, NHEADS * HID / 64), 256, 0, stream>>>(
            adj, Wh1, f1a, f2a, partA, partS);
    reduce_kernel<<<dim3(N / 256, 256), 256, 0, stream>>>(
        partA, partS, h1T, 256, NHEADS, N, 1);

    // ---- layer 2 ----
    gemm2_kernel<<<N / 8, 256, 0, stream>>>(h1T, W2, Wh2v);
    fkern2<<<N, 128, 0, stream>>>(Wh2v, a2, f1b, f2b);
    attn_kernel<1, OUT_DIM>
        <<<dim3(N / 64, JSPLIT, OUT_DIM / 64), 256, 0, stream>>>(
            adj, Wh2v, f1b, f2b, partA, partS);
    reduce_kernel<<<dim3(N / 256, 128), 256, 0, stream>>>(
        partA, partS, out, 128, 1, 1, 128);
}

// Round 3
// 276.686 us; speedup vs baseline: 3.8757x; 3.8757x over previous
//
#include <hip/hip_runtime.h>
#include <hip/hip_bf16.h>

#define N 4096
#define IN_DIM 256
#define HID 64
#define NHEADS 4
#define OUT_DIM 128

typedef __attribute__((ext_vector_type(8))) short bf16x8;
typedef __attribute__((ext_vector_type(4))) float f32x4;

// ---------------------------------------------------------------------------
// gemm1: x[N,256] @ W_heads[4][256][64] -> Wh1[4][N][64] fp32
//        + WhT1[4][64][N] bf16 (B-operand layout for MFMA attn)
// ---------------------------------------------------------------------------
__global__ void gemm1_kernel(const float* __restrict__ x,
                             const float* __restrict__ W,
                             float* __restrict__ Wh,
                             __hip_bfloat16* __restrict__ WhT) {
    __shared__ float xs[8 * IN_DIM];
    const int t = threadIdx.x;
    const int c = t & 63, h = t >> 6;
    const int i0 = blockIdx.x * 8;
    const float4* xg = (const float4*)(x + (size_t)i0 * IN_DIM);
    float4* xs4 = (float4*)xs;
    for (int u = t; u < 8 * IN_DIM / 4; u += 256) xs4[u] = xg[u];
    __syncthreads();
    float acc[8];
#pragma unroll
    for (int r = 0; r < 8; r++) acc[r] = 0.f;
    const float* Wp = W + (size_t)h * IN_DIM * HID + c;
    for (int k = 0; k < IN_DIM; k += 4) {
        const float w0 = Wp[(size_t)(k + 0) * HID];
        const float w1 = Wp[(size_t)(k + 1) * HID];
        const float w2 = Wp[(size_t)(k + 2) * HID];
        const float w3 = Wp[(size_t)(k + 3) * HID];
#pragma unroll
        for (int r = 0; r < 8; r++) {
            const float4 xv = *(const float4*)(xs + r * IN_DIM + k);
            acc[r] += xv.x * w0 + xv.y * w1 + xv.z * w2 + xv.w * w3;
        }
    }
#pragma unroll
    for (int r = 0; r < 8; r++)
        Wh[((size_t)h * N + (i0 + r)) * HID + c] = acc[r];
    union { ushort u[8]; uint4 v; } cv;
#pragma unroll
    for (int r = 0; r < 8; r++)
        cv.u[r] = __hip_bfloat16_raw(__float2bfloat16(acc[r])).x;
    *(uint4*)(WhT + ((size_t)h * HID + c) * N + i0) = cv.v;
}

// ---------------------------------------------------------------------------
// mask_kernel: pack adj>0 into bitmask. maskb[i] has N/32 uint32 words,
// bit b of word w = adj[i][w*32+b]. One block per row, ballot per wave.
// ---------------------------------------------------------------------------
__global__ void mask_kernel(const int* __restrict__ adj,
                            unsigned long long* __restrict__ maskb64) {
    const int i = blockIdx.x;
    const int lane = threadIdx.x & 63, w = threadIdx.x >> 6;
    for (int it = 0; it < N / 256; it++) {
        const int j = (it * 4 + w) * 64 + lane;
        const int a = adj[(size_t)i * N + j];
        const unsigned long long b = __ballot(a > 0);
        if (lane == 0) maskb64[(size_t)i * (N / 64) + it * 4 + w] = b;
    }
}

// ---------------------------------------------------------------------------
// fkern1 / fkern2: attention projections f1,f2 (unchanged semantics)
// ---------------------------------------------------------------------------
__global__ void fkern1(const float* __restrict__ Wh, const float* __restrict__ a,
                       float* __restrict__ f1, float* __restrict__ f2) {
    const int i = blockIdx.x;
    const int t = threadIdx.x;
    const int h = t >> 6, c = t & 63;
    const float v = Wh[((size_t)h * N + i) * HID + c];
    float v1 = v * a[h * 2 * HID + c];
    float v2 = v * a[h * 2 * HID + HID + c];
#pragma unroll
    for (int m = 32; m > 0; m >>= 1) {
        v1 += __shfl_xor(v1, m, 64);
        v2 += __shfl_xor(v2, m, 64);
    }
    if (c == 0) { f1[(size_t)h * N + i] = v1; f2[(size_t)h * N + i] = v2; }
}

__global__ void fkern2(const float* __restrict__ Wh2, const float* __restrict__ a2,
                       float* __restrict__ f1, float* __restrict__ f2) {
    __shared__ float red[4];
    const int i = blockIdx.x, t = threadIdx.x;
    const float v = Wh2[(size_t)i * OUT_DIM + t];
    float v1 = v * a2[t];
    float v2 = v * a2[OUT_DIM + t];
#pragma unroll
    for (int m = 32; m > 0; m >>= 1) {
        v1 += __shfl_xor(v1, m, 64);
        v2 += __shfl_xor(v2, m, 64);
    }
    const int w = t >> 6;
    if ((t & 63) == 0) { red[w * 2] = v1; red[w * 2 + 1] = v2; }
    __syncthreads();
    if (t == 0) { f1[i] = red[0] + red[2]; f2[i] = red[1] + red[3]; }
}

// ---------------------------------------------------------------------------
// MFMA attention: per wave, MW A-tiles of 16 rows; K-loop over j in steps of
// 32 (mfma_f32_16x16x32_bf16). P computed in-register from f1/f2 + bitmask,
// converted bf16. B-frags loaded directly from WhT[h][c][j] (bf16, k-contig;
// 4 block-waves share (h, j-chunk) -> L1 reuse). Softmax denom via ones-B
// MFMA (same C/D row layout as acc -> lane-local divide later).
// A/B k-permutation assumptions cancel (symmetric operands); C/D layout is
// the HW-verified col=lane&15, row=quad*4+reg.
// grid: (N/(64*MW), JS, HEADS); block 256.
// ---------------------------------------------------------------------------
template <int HEADS, int D, int JS, int MW>
__global__ __launch_bounds__(256, 4) void attn_mfma(
        const unsigned* __restrict__ maskb,             // [N][N/32]
        const __hip_bfloat16* __restrict__ WhT,          // [HEADS][D][N]
        const float* __restrict__ f1g, const float* __restrict__ f2g,
        float* __restrict__ partA, float* __restrict__ partS) {
    constexpr int CT = D / 16;
    constexpr int KSTEPS = N / (32 * JS);
    const int t = threadIdx.x;
    const int w = t >> 6, lane = t & 63;
    const int m = lane & 15, quad = lane >> 4;
    const int h = blockIdx.z;
    const int i0w = blockIdx.x * (64 * MW) + w * (16 * MW);
    const int split = blockIdx.y;
    const int jbase = split * (N / JS);

    float f1v[MW];
    int mrow[MW];
#pragma unroll
    for (int mw = 0; mw < MW; mw++) {
        f1v[mw] = f1g[(size_t)h * N + i0w + mw * 16 + m];
        mrow[mw] = (i0w + mw * 16 + m) * (N / 32);
    }

    const f32x4 zero = {0.f, 0.f, 0.f, 0.f};
    f32x4 acc[MW][CT];
    f32x4 sac[MW];
#pragma unroll
    for (int mw = 0; mw < MW; mw++) {
        sac[mw] = zero;
#pragma unroll
        for (int ct = 0; ct < CT; ct++) acc[mw][ct] = zero;
    }
    const short one_bf = (short)0x3F80;
    const bf16x8 ones = {one_bf, one_bf, one_bf, one_bf,
                         one_bf, one_bf, one_bf, one_bf};

    const float* f2p = f2g + (size_t)h * N;
    const __hip_bfloat16* whbase = WhT + (size_t)h * D * N;

    for (int ks = 0; ks < KSTEPS; ks++) {
        const int j0 = jbase + ks * 32;
        const int jq = j0 + quad * 8;
        const float4 f2lo = *(const float4*)(f2p + jq);
        const float4 f2hi = *(const float4*)(f2p + jq + 4);
        const float f2v[8] = {f2lo.x, f2lo.y, f2lo.z, f2lo.w,
                              f2hi.x, f2hi.y, f2hi.z, f2hi.w};
        unsigned mwrd[MW];
#pragma unroll
        for (int mw = 0; mw < MW; mw++) mwrd[mw] = maskb[mrow[mw] + (j0 >> 5)];

        bf16x8 afr[MW];
#pragma unroll
        for (int mw = 0; mw < MW; mw++) {
            float p[8];
#pragma unroll
            for (int e = 0; e < 8; e++) {
                const float tt = f1v[mw] + f2v[e];
                const float lr = fmaxf(tt, 0.5f * tt);     // LeakyReLU(0.5)
                const float pe = __expf(lr);
                p[e] = ((mwrd[mw] >> (quad * 8 + e)) & 1u) ? pe : 0.f;
            }
            union { bf16x8 v; __hip_bfloat162 h2[4]; } u;
#pragma unroll
            for (int e2 = 0; e2 < 4; e2++)
                u.h2[e2] = __float22bfloat162_rn(
                    make_float2(p[2 * e2], p[2 * e2 + 1]));
            afr[mw] = u.v;
        }

#pragma unroll
        for (int ct = 0; ct < CT; ct++) {
            const bf16x8 b =
                *(const bf16x8*)(whbase + (size_t)(ct * 16 + m) * N + jq);
#pragma unroll
            for (int mw = 0; mw < MW; mw++)
                acc[mw][ct] = __builtin_amdgcn_mfma_f32_16x16x32_bf16(
                    afr[mw], b, acc[mw][ct], 0, 0, 0);
        }
#pragma unroll
        for (int mw = 0; mw < MW; mw++)
            sac[mw] = __builtin_amdgcn_mfma_f32_16x16x32_bf16(
                afr[mw], ones, sac[mw], 0, 0, 0);
    }

    // epilogue: partials. channel = h*D + ct*16 + m ; row i = i0w+mw*16+quad*4+r
#pragma unroll
    for (int mw = 0; mw < MW; mw++) {
#pragma unroll
        for (int ct = 0; ct < CT; ct++) {
#pragma unroll
            for (int r = 0; r < 4; r++)
                partA[((size_t)split * (HEADS * D) + h * D + ct * 16 + m) * N +
                      (i0w + mw * 16 + quad * 4 + r)] = acc[mw][ct][r];
        }
        if (m == 0) {
#pragma unroll
            for (int r = 0; r < 4; r++)
                partS[((size_t)split * HEADS + h) * N +
                      (i0w + mw * 16 + quad * 4 + r)] = sac[mw][r];
        }
    }
}

// ---------------------------------------------------------------------------
// reduce: combine j-split partials, divide by denom, ELU.
// ---------------------------------------------------------------------------
__global__ void reduce_kernel(const float* __restrict__ partA,
                              const float* __restrict__ partS,
                              float* __restrict__ outp, int OUTW, int NH,
                              int js, int strideC, int strideI) {
    const int i = blockIdx.x * 256 + threadIdx.x;
    const int hc = blockIdx.y;
    const int hd = hc / (OUTW / NH);
    float a = 0.f, ss = 0.f;
    for (int sp = 0; sp < js; sp++) {
        a  += partA[((size_t)sp * OUTW + hc) * N + i];
        ss += partS[((size_t)sp * NH + hd) * N + i];
    }
    float v = a / ss;
    v = (v > 0.f) ? v : (__expf(v) - 1.f);       // ELU
    outp[(size_t)hc * strideC + (size_t)i * strideI] = v;
}

// ---------------------------------------------------------------------------
// gemm2: h1T[256][N] (k-major) @ W_out[256][128] -> Wh2[N][128] fp32
//        + WhT2[128][N] bf16
// ---------------------------------------------------------------------------
__global__ void gemm2_kernel(const float* __restrict__ h1T,
                             const float* __restrict__ W2,
                             float* __restrict__ Wh2,
                             __hip_bfloat16* __restrict__ WhT2) {
    __shared__ float hs[8 * IN_DIM];
    const int t = threadIdx.x;
    const int c = t & 127, rh = t >> 7;
    const int i0 = blockIdx.x * 8;
    for (int u = t; u < 8 * IN_DIM; u += 256) {
        const int r = u & 7, k = u >> 3;
        hs[r * IN_DIM + k] = h1T[(size_t)k * N + i0 + r];
    }
    __syncthreads();
    float acc[4];
#pragma unroll
    for (int rr = 0; rr < 4; rr++) acc[rr] = 0.f;
    for (int k = 0; k < IN_DIM; k += 4) {
        const float w0 = W2[(size_t)(k + 0) * OUT_DIM + c];
        const float w1 = W2[(size_t)(k + 1) * OUT_DIM + c];
        const float w2 = W2[(size_t)(k + 2) * OUT_DIM + c];
        const float w3 = W2[(size_t)(k + 3) * OUT_DIM + c];
#pragma unroll
        for (int rr = 0; rr < 4; rr++) {
            const float4 hv = *(const float4*)(hs + (rh * 4 + rr) * IN_DIM + k);
            acc[rr] += hv.x * w0 + hv.y * w1 + hv.z * w2 + hv.w * w3;
        }
    }
#pragma unroll
    for (int rr = 0; rr < 4; rr++)
        Wh2[(size_t)(i0 + rh * 4 + rr) * OUT_DIM + c] = acc[rr];
    union { ushort u[4]; uint2 v; } cv;
#pragma unroll
    for (int rr = 0; rr < 4; rr++)
        cv.u[rr] = __hip_bfloat16_raw(__float2bfloat16(acc[rr])).x;
    *(uint2*)(WhT2 + (size_t)c * N + i0 + rh * 4) = cv.v;
}

// ---------------------------------------------------------------------------
extern "C" void kernel_launch(void* const* d_in, const int* in_sizes, int n_in,
                              void* d_out, int out_size, void* d_ws, size_t ws_size,
                              hipStream_t stream) {
    const float* x   = (const float*)d_in[0];
    const int*   adj = (const int*)d_in[1];
    const float* Wh_ = (const float*)d_in[2];
    const float* ah  = (const float*)d_in[3];
    const float* W2  = (const float*)d_in[4];
    const float* a2  = (const float*)d_in[5];
    float* out = (float*)d_out;

    float* ws = (float*)d_ws;
    float* Wh1   = ws;                                   // 4*N*64    fp32
    float* f1a   = Wh1 + (size_t)NHEADS * N * HID;       // 4*N
    float* f2a   = f1a + (size_t)NHEADS * N;             // 4*N
    float* h1T   = f2a + (size_t)NHEADS * N;             // 256*N
    float* Wh2v  = h1T + (size_t)IN_DIM * N;             // N*128
    float* f1b   = Wh2v + (size_t)N * OUT_DIM;           // N
    float* f2b   = f1b + N;                              // N
    __hip_bfloat16* WhT1 = (__hip_bfloat16*)(f2b + N);               // 4*64*N bf16
    __hip_bfloat16* WhT2 = WhT1 + (size_t)NHEADS * HID * N;          // 128*N bf16
    unsigned* maskb = (unsigned*)(WhT2 + (size_t)OUT_DIM * N);       // N*128 u32
    float* partA = (float*)(maskb + (size_t)N * (N / 32));  // 2048*N fp32 (32MB)
    float* partS = partA + (size_t)2048 * N;                // 32*N

    // ---- shared precompute ----
    mask_kernel<<<N, 256, 0, stream>>>(adj, (unsigned long long*)maskb);

    // ---- layer 1 ----
    gemm1_kernel<<<N / 8, 256, 0, stream>>>(x, Wh_, Wh1, WhT1);
    fkern1<<<N, 256, 0, stream>>>(Wh1, ah, f1a, f2a);
    attn_mfma<NHEADS, HID, 8, 2>
        <<<dim3(N / 128, 8, NHEADS), 256, 0, stream>>>(
            maskb, WhT1, f1a, f2a, partA, partS);
    reduce_kernel<<<dim3(N / 256, 256), 256, 0, stream>>>(
        partA, partS, h1T, 256, NHEADS, 8, N, 1);

    // ---- layer 2 ----
    gemm2_kernel<<<N / 8, 256, 0, stream>>>(h1T, W2, Wh2v, WhT2);
    fkern2<<<N, 128, 0, stream>>>(Wh2v, a2, f1b, f2b);
    attn_mfma<1, OUT_DIM, 16, 1>
        <<<dim3(N / 64, 16, 1), 256, 0, stream>>>(
            maskb, WhT2, f1b, f2b, partA, partS);
    reduce_kernel<<<dim3(N / 256, 128), 256, 0, stream>>>(
        partA, partS, out, 128, 1, 16, 1, 128);
}

// Round 4
// 242.239 us; speedup vs baseline: 4.4268x; 1.1422x over previous
//
#include <hip/hip_runtime.h>
#include <hip/hip_bf16.h>

#define N 4096
#define IN_DIM 256
#define HID 64
#define NHEADS 4
#define OUT_DIM 128
#define LOG2E 1.44269504088896340736f

typedef __attribute__((ext_vector_type(8))) short bf16x8;
typedef __attribute__((ext_vector_type(4))) float f32x4;

// ---------------------------------------------------------------------------
// gemm1: x[N,256] @ W_heads[4][256][64] -> Wh1[4][N][64] fp32
//        + WhB1: MFMA-B-fragment layout [h][j/32][ct(4)][lane(64)][e(8)] bf16
// Thread (h,c) rows i0..i0+7 => e=r, quad=(i0>>3)&3, lane=(c&15)+16*quad.
// ---------------------------------------------------------------------------
__global__ void gemm1_kernel(const float* __restrict__ x,
                             const float* __restrict__ W,
                             float* __restrict__ Wh,
                             __hip_bfloat16* __restrict__ WhB) {
    __shared__ float xs[8 * IN_DIM];
    const int t = threadIdx.x;
    const int c = t & 63, h = t >> 6;
    const int i0 = blockIdx.x * 8;
    const float4* xg = (const float4*)(x + (size_t)i0 * IN_DIM);
    float4* xs4 = (float4*)xs;
    for (int u = t; u < 8 * IN_DIM / 4; u += 256) xs4[u] = xg[u];
    __syncthreads();
    float acc[8];
#pragma unroll
    for (int r = 0; r < 8; r++) acc[r] = 0.f;
    const float* Wp = W + (size_t)h * IN_DIM * HID + c;
    for (int k = 0; k < IN_DIM; k += 4) {
        const float w0 = Wp[(size_t)(k + 0) * HID];
        const float w1 = Wp[(size_t)(k + 1) * HID];
        const float w2 = Wp[(size_t)(k + 2) * HID];
        const float w3 = Wp[(size_t)(k + 3) * HID];
#pragma unroll
        for (int r = 0; r < 8; r++) {
            const float4 xv = *(const float4*)(xs + r * IN_DIM + k);
            acc[r] += xv.x * w0 + xv.y * w1 + xv.z * w2 + xv.w * w3;
        }
    }
#pragma unroll
    for (int r = 0; r < 8; r++)
        Wh[((size_t)h * N + (i0 + r)) * HID + c] = acc[r];
    union { ushort u[8]; uint4 v; } cv;
#pragma unroll
    for (int r = 0; r < 8; r++)
        cv.u[r] = __hip_bfloat16_raw(__float2bfloat16(acc[r])).x;
    const int jblk = i0 >> 5, quad = (i0 >> 3) & 3;
    const int lane_idx = (c & 15) + 16 * quad;
    *(uint4*)(WhB + ((((size_t)h * (N / 32) + jblk) * 4 + (c >> 4)) * 64 +
                     lane_idx) * 8) = cv.v;
}

// ---------------------------------------------------------------------------
// mask_kernel: transposed bitmask maskT[jw][i] (u32), bit b = adj[i][jw*32+b].
// Coalesced adj reads (lane = j), ballot per row.
// grid (N/64 j-tiles, N/64 i-tiles), block 256 (4 waves x 16 rows).
// ---------------------------------------------------------------------------
__global__ void mask_kernel(const int* __restrict__ adj,
                            unsigned* __restrict__ maskT) {
    const int lane = threadIdx.x & 63, w = threadIdx.x >> 6;
    const int j0 = blockIdx.x * 64;
    const int i0 = blockIdx.y * 64 + w * 16;
    const int jw0 = j0 >> 5;
    for (int rr = 0; rr < 16; rr++) {
        const int i = i0 + rr;
        const int a = adj[(size_t)i * N + j0 + lane];
        const unsigned long long b = __ballot(a > 0);
        if (lane == 0) {
            maskT[(size_t)jw0 * N + i] = (unsigned)b;
            maskT[(size_t)(jw0 + 1) * N + i] = (unsigned)(b >> 32);
        }
    }
}

// ---------------------------------------------------------------------------
// fkern1 / fkern2: f1,f2 projections, PRE-SCALED by log2e (so attn uses raw
// v_exp_f32 as exp2). Scaling commutes with LeakyReLU (positive scale).
// ---------------------------------------------------------------------------
__global__ void fkern1(const float* __restrict__ Wh, const float* __restrict__ a,
                       float* __restrict__ f1, float* __restrict__ f2) {
    const int i = blockIdx.x;
    const int t = threadIdx.x;
    const int h = t >> 6, c = t & 63;
    const float v = Wh[((size_t)h * N + i) * HID + c];
    float v1 = v * a[h * 2 * HID + c];
    float v2 = v * a[h * 2 * HID + HID + c];
#pragma unroll
    for (int m = 32; m > 0; m >>= 1) {
        v1 += __shfl_xor(v1, m, 64);
        v2 += __shfl_xor(v2, m, 64);
    }
    if (c == 0) {
        f1[(size_t)h * N + i] = v1 * LOG2E;
        f2[(size_t)h * N + i] = v2 * LOG2E;
    }
}

__global__ void fkern2(const float* __restrict__ Wh2, const float* __restrict__ a2,
                       float* __restrict__ f1, float* __restrict__ f2) {
    __shared__ float red[4];
    const int i = blockIdx.x, t = threadIdx.x;
    const float v = Wh2[(size_t)i * OUT_DIM + t];
    float v1 = v * a2[t];
    float v2 = v * a2[OUT_DIM + t];
#pragma unroll
    for (int m = 32; m > 0; m >>= 1) {
        v1 += __shfl_xor(v1, m, 64);
        v2 += __shfl_xor(v2, m, 64);
    }
    const int w = t >> 6;
    if ((t & 63) == 0) { red[w * 2] = v1; red[w * 2 + 1] = v2; }
    __syncthreads();
    if (t == 0) {
        f1[i] = (red[0] + red[2]) * LOG2E;
        f2[i] = (red[1] + red[3]) * LOG2E;
    }
}

// ---------------------------------------------------------------------------
// MFMA attention, round 4:
//  - B in fragment-native layout -> 1KB fully-coalesced wave loads
//  - transposed bitmask -> 64B coalesced broadcast load
//  - z = head*DSL + d-slice; each block: 16-row waves x 64 rows, CTT ct-tiles
//  - B-frags loaded BEFORE P-gen so ~150cyc VALU covers VMEM latency
// grid (N/64, JS, HEADS*DSL), block 256. KSTEPS = N/(32*JS).
// ---------------------------------------------------------------------------
template <int HEADS, int DSL, int CTT, int JS, int D>
__global__ __launch_bounds__(256, 4) void attn_mfma(
        const unsigned* __restrict__ maskT,             // [N/32][N]
        const __hip_bfloat16* __restrict__ WhB,          // [H][N/32][D/16][64][8]
        const float* __restrict__ f1g, const float* __restrict__ f2g,
        float* __restrict__ partA, float* __restrict__ partS) {
    constexpr int CTOT = D / 16;
    constexpr int KSTEPS = N / (32 * JS);
    const int t = threadIdx.x;
    const int w = t >> 6, lane = t & 63;
    const int m = lane & 15, quad = lane >> 4;
    const int z = blockIdx.z;
    const int h = z / DSL, slc = z % DSL;
    const int i0w = blockIdx.x * 64 + w * 16;
    const int i = i0w + m;
    const int split = blockIdx.y;
    const int jbase = split * (N / JS);

    const float f1v = f1g[(size_t)h * N + i];
    const float* f2p = f2g + (size_t)h * N;
    const bf16x8* whb = (const bf16x8*)WhB + ((size_t)h * (N / 32)) * CTOT * 64;

    const f32x4 zero = {0.f, 0.f, 0.f, 0.f};
    f32x4 acc[CTT];
    f32x4 sac = zero;
#pragma unroll
    for (int ct = 0; ct < CTT; ct++) acc[ct] = zero;
    const short one_bf = (short)0x3F80;
    const bf16x8 ones = {one_bf, one_bf, one_bf, one_bf,
                         one_bf, one_bf, one_bf, one_bf};

    for (int ks = 0; ks < KSTEPS; ks++) {
        const int j0 = jbase + ks * 32;
        const int jw = j0 >> 5;

        // ---- issue all loads first ----
        const unsigned mwrd = maskT[(size_t)jw * N + i];
        const float4 f2lo = *(const float4*)(f2p + j0 + quad * 8);
        const float4 f2hi = *(const float4*)(f2p + j0 + quad * 8 + 4);
        bf16x8 bfrag[CTT];
        const bf16x8* bp = whb + ((size_t)jw * CTOT + slc * CTT) * 64 + lane;
#pragma unroll
        for (int ct = 0; ct < CTT; ct++) bfrag[ct] = bp[ct * 64];

        // ---- P-gen (covers load latency) ----
        const float f2v[8] = {f2lo.x, f2lo.y, f2lo.z, f2lo.w,
                              f2hi.x, f2hi.y, f2hi.z, f2hi.w};
        float p[8];
#pragma unroll
        for (int e = 0; e < 8; e++) {
            const float tt = f1v + f2v[e];
            const float lr = fmaxf(tt, 0.5f * tt);        // LeakyReLU(0.5)
            const float pe = __builtin_amdgcn_exp2f(lr);  // exp(x), log2e folded
            p[e] = ((mwrd >> (quad * 8 + e)) & 1u) ? pe : 0.f;
        }
        union { bf16x8 v; __hip_bfloat162 h2[4]; } u;
#pragma unroll
        for (int e2 = 0; e2 < 4; e2++)
            u.h2[e2] = __float22bfloat162_rn(
                make_float2(p[2 * e2], p[2 * e2 + 1]));
        const bf16x8 afr = u.v;

        // ---- MFMAs ----
#pragma unroll
        for (int ct = 0; ct < CTT; ct++)
            acc[ct] = __builtin_amdgcn_mfma_f32_16x16x32_bf16(
                afr, bfrag[ct], acc[ct], 0, 0, 0);
        sac = __builtin_amdgcn_mfma_f32_16x16x32_bf16(afr, ones, sac, 0, 0, 0);
    }

    // epilogue: channel = h*D + (slc*CTT+ct)*16 + m ; row = i0w+quad*4+r
#pragma unroll
    for (int ct = 0; ct < CTT; ct++) {
        const int ch = h * D + (slc * CTT + ct) * 16 + m;
#pragma unroll
        for (int r = 0; r < 4; r++)
            partA[((size_t)split * (HEADS * D) + ch) * N +
                  (i0w + quad * 4 + r)] = acc[ct][r];
    }
    if (slc == 0 && m == 0) {
#pragma unroll
        for (int r = 0; r < 4; r++)
            partS[((size_t)split * HEADS + h) * N + (i0w + quad * 4 + r)] = sac[r];
    }
}

// ---------------------------------------------------------------------------
// reduce: combine j-split partials, divide by denom, ELU.
// ---------------------------------------------------------------------------
__global__ void reduce_kernel(const float* __restrict__ partA,
                              const float* __restrict__ partS,
                              float* __restrict__ outp, int OUTW, int NH,
                              int js, int strideC, int strideI) {
    const int i = blockIdx.x * 256 + threadIdx.x;
    const int hc = blockIdx.y;
    const int hd = hc / (OUTW / NH);
    float a = 0.f, ss = 0.f;
    for (int sp = 0; sp < js; sp++) {
        a  += partA[((size_t)sp * OUTW + hc) * N + i];
        ss += partS[((size_t)sp * NH + hd) * N + i];
    }
    float v = a / ss;
    v = (v > 0.f) ? v : (__expf(v) - 1.f);       // ELU
    outp[(size_t)hc * strideC + (size_t)i * strideI] = v;
}

// ---------------------------------------------------------------------------
// gemm2: h1T[256][N] (k-major) @ W_out[256][128] -> Wh2[N][128] fp32
//        + WhB2 fragment layout [j/32][ct(8)][lane][e] bf16
// ---------------------------------------------------------------------------
__global__ void gemm2_kernel(const float* __restrict__ h1T,
                             const float* __restrict__ W2,
                             float* __restrict__ Wh2,
                             __hip_bfloat16* __restrict__ WhB2) {
    __shared__ float hs[8 * IN_DIM];
    const int t = threadIdx.x;
    const int c = t & 127, rh = t >> 7;
    const int i0 = blockIdx.x * 8;
    for (int u = t; u < 8 * IN_DIM; u += 256) {
        const int r = u & 7, k = u >> 3;
        hs[r * IN_DIM + k] = h1T[(size_t)k * N + i0 + r];
    }
    __syncthreads();
    float acc[4];
#pragma unroll
    for (int rr = 0; rr < 4; rr++) acc[rr] = 0.f;
    for (int k = 0; k < IN_DIM; k += 4) {
        const float w0 = W2[(size_t)(k + 0) * OUT_DIM + c];
        const float w1 = W2[(size_t)(k + 1) * OUT_DIM + c];
        const float w2 = W2[(size_t)(k + 2) * OUT_DIM + c];
        const float w3 = W2[(size_t)(k + 3) * OUT_DIM + c];
#pragma unroll
        for (int rr = 0; rr < 4; rr++) {
            const float4 hv = *(const float4*)(hs + (rh * 4 + rr) * IN_DIM + k);
            acc[rr] += hv.x * w0 + hv.y * w1 + hv.z * w2 + hv.w * w3;
        }
    }
#pragma unroll
    for (int rr = 0; rr < 4; rr++)
        Wh2[(size_t)(i0 + rh * 4 + rr) * OUT_DIM + c] = acc[rr];
    union { ushort u[4]; uint2 v; } cv;
#pragma unroll
    for (int rr = 0; rr < 4; rr++)
        cv.u[rr] = __hip_bfloat16_raw(__float2bfloat16(acc[rr])).x;
    const int jblk = i0 >> 5, quad = (i0 >> 3) & 3;
    const int lane_idx = (c & 15) + 16 * quad;
    *(uint2*)((__hip_bfloat16*)WhB2 +
              (((size_t)jblk * 8 + (c >> 4)) * 64 + lane_idx) * 8 + rh * 4) = cv.v;
}

// ---------------------------------------------------------------------------
extern "C" void kernel_launch(void* const* d_in, const int* in_sizes, int n_in,
                              void* d_out, int out_size, void* d_ws, size_t ws_size,
                              hipStream_t stream) {
    const float* x   = (const float*)d_in[0];
    const int*   adj = (const int*)d_in[1];
    const float* Wh_ = (const float*)d_in[2];
    const float* ah  = (const float*)d_in[3];
    const float* W2  = (const float*)d_in[4];
    const float* a2  = (const float*)d_in[5];
    float* out = (float*)d_out;

    float* ws = (float*)d_ws;
    float* Wh1   = ws;                                   // 4*N*64 fp32 (4MB)
    float* f1a   = Wh1 + (size_t)NHEADS * N * HID;
    float* f2a   = f1a + (size_t)NHEADS * N;
    float* h1T   = f2a + (size_t)NHEADS * N;             // 256*N (4MB)
    float* Wh2v  = h1T + (size_t)IN_DIM * N;             // N*128 (2MB)
    float* f1b   = Wh2v + (size_t)N * OUT_DIM;
    float* f2b   = f1b + N;
    __hip_bfloat16* WhB1 = (__hip_bfloat16*)(f2b + N);           // 4*64*N bf16
    __hip_bfloat16* WhB2 = WhB1 + (size_t)NHEADS * HID * N;      // 128*N bf16
    unsigned* maskT = (unsigned*)(WhB2 + (size_t)OUT_DIM * N);   // (N/32)*N u32
    float* partA = (float*)(maskT + (size_t)(N / 32) * N);  // 16*128*N fl (33MB)
    float* partS = partA + (size_t)16 * OUT_DIM * N;        // 16*4*N

    // ---- shared precompute ----
    mask_kernel<<<dim3(N / 64, N / 64), 256, 0, stream>>>(adj, maskT);

    // ---- layer 1 ----
    gemm1_kernel<<<N / 8, 256, 0, stream>>>(x, Wh_, Wh1, WhB1);
    fkern1<<<N, 256, 0, stream>>>(Wh1, ah, f1a, f2a);
    attn_mfma<NHEADS, 1, 4, 8, HID>
        <<<dim3(N / 64, 8, NHEADS), 256, 0, stream>>>(
            maskT, WhB1, f1a, f2a, partA, partS);
    reduce_kernel<<<dim3(N / 256, 256), 256, 0, stream>>>(
        partA, partS, h1T, 256, NHEADS, 8, N, 1);

    // ---- layer 2 ----
    gemm2_kernel<<<N / 8, 256, 0, stream>>>(h1T, W2, Wh2v, WhB2);
    fkern2<<<N, 128, 0, stream>>>(Wh2v, a2, f1b, f2b);
    attn_mfma<1, 2, 4, 16, OUT_DIM>
        <<<dim3(N / 64, 16, 2), 256, 0, stream>>>(
            maskT, WhB2, f1b, f2b, partA, partS);
    reduce_kernel<<<dim3(N / 256, 128), 256, 0, stream>>>(
        partA, partS, out, 128, 1, 16, 1, 128);
}

// Round 5
// 200.484 us; speedup vs baseline: 5.3488x; 1.2083x over previous
//
#include <hip/hip_runtime.h>
#include <hip/hip_bf16.h>

#define N 4096
#define IN_DIM 256
#define HID 64
#define NHEADS 4
#define OUT_DIM 128
#define LOG2E 1.44269504088896340736f

typedef __attribute__((ext_vector_type(8))) short bf16x8;
typedef __attribute__((ext_vector_type(4))) float f32x4;

// ---------------------------------------------------------------------------
// gemm1: x[N,256] @ W_heads[4][256][64] -> WhB1 (MFMA-B-fragment bf16 layout
// [h][j/32][ct(4)][lane(64)][e(8)]) + fused f1/f2 projections (from fp32 acc,
// pre-scaled by log2e). No fp32 Wh store.
// block 256: h = t>>6, c = t&63; rows i0..i0+7.
// ---------------------------------------------------------------------------
__global__ void gemm1_kernel(const float* __restrict__ x,
                             const float* __restrict__ W,
                             const float* __restrict__ a,
                             __hip_bfloat16* __restrict__ WhB,
                             float* __restrict__ f1, float* __restrict__ f2) {
    __shared__ float xs[8 * IN_DIM];
    const int t = threadIdx.x;
    const int c = t & 63, h = t >> 6;
    const int i0 = blockIdx.x * 8;
    const float4* xg = (const float4*)(x + (size_t)i0 * IN_DIM);
    float4* xs4 = (float4*)xs;
    for (int u = t; u < 8 * IN_DIM / 4; u += 256) xs4[u] = xg[u];
    __syncthreads();
    float acc[8];
#pragma unroll
    for (int r = 0; r < 8; r++) acc[r] = 0.f;
    const float* Wp = W + (size_t)h * IN_DIM * HID + c;
    for (int k = 0; k < IN_DIM; k += 4) {
        const float w0 = Wp[(size_t)(k + 0) * HID];
        const float w1 = Wp[(size_t)(k + 1) * HID];
        const float w2 = Wp[(size_t)(k + 2) * HID];
        const float w3 = Wp[(size_t)(k + 3) * HID];
#pragma unroll
        for (int r = 0; r < 8; r++) {
            const float4 xv = *(const float4*)(xs + r * IN_DIM + k);
            acc[r] += xv.x * w0 + xv.y * w1 + xv.z * w2 + xv.w * w3;
        }
    }
    // bf16 fragment store
    union { ushort u[8]; uint4 v; } cv;
#pragma unroll
    for (int r = 0; r < 8; r++)
        cv.u[r] = __hip_bfloat16_raw(__float2bfloat16(acc[r])).x;
    const int jblk = i0 >> 5, quad = (i0 >> 3) & 3;
    const int lane_idx = (c & 15) + 16 * quad;
    *(uint4*)(WhB + ((((size_t)h * (N / 32) + jblk) * 4 + (c >> 4)) * 64 +
                     lane_idx) * 8) = cv.v;
    // fused f1/f2: wave-reduce acc[r]*a over c (64 lanes = one head)
    const float av1 = a[h * 2 * HID + c];
    const float av2 = a[h * 2 * HID + HID + c];
    float s1[8], s2[8];
#pragma unroll
    for (int r = 0; r < 8; r++) { s1[r] = acc[r] * av1; s2[r] = acc[r] * av2; }
#pragma unroll
    for (int mm = 32; mm > 0; mm >>= 1) {
#pragma unroll
        for (int r = 0; r < 8; r++) {
            s1[r] += __shfl_xor(s1[r], mm, 64);
            s2[r] += __shfl_xor(s2[r], mm, 64);
        }
    }
    if (c == 0) {
#pragma unroll
        for (int r = 0; r < 8; r++) {
            f1[(size_t)h * N + i0 + r] = s1[r] * LOG2E;
            f2[(size_t)h * N + i0 + r] = s2[r] * LOG2E;
        }
    }
}

// ---------------------------------------------------------------------------
// mask_kernel: transposed bitmask maskT[jw][i], bit b = adj[i][jw*32+b]>0.
// grid (N/64 j-tiles, N/16 i-tiles), block 256 (4 waves x 4 rows each).
// ---------------------------------------------------------------------------
__global__ void mask_kernel(const int* __restrict__ adj,
                            unsigned* __restrict__ maskT) {
    const int lane = threadIdx.x & 63, w = threadIdx.x >> 6;
    const int j0 = blockIdx.x * 64;
    const int i0 = blockIdx.y * 16 + w * 4;
    const int jw0 = j0 >> 5;
#pragma unroll
    for (int rr = 0; rr < 4; rr++) {
        const int i = i0 + rr;
        const int av = adj[(size_t)i * N + j0 + lane];
        const unsigned long long b = __ballot(av > 0);
        if (lane == 0) {
            maskT[(size_t)jw0 * N + i] = (unsigned)b;
            maskT[(size_t)(jw0 + 1) * N + i] = (unsigned)(b >> 32);
        }
    }
}

// ---------------------------------------------------------------------------
// Fused attention layer: P-gen (bitmask+exp2) -> MFMA -> in-block LDS
// reduction over j-groups -> softmax divide -> ELU -> final store.
// Block: G waves, all same 16 rows (i0..i0+15); wave g covers j range
// [g*N/G, (g+1)*N/G). No partial HBM traffic, no separate reduce kernel.
// L1: HEADS=4, D=64,  G=8  (512 thr, 1024 blocks) -> writes h1T[ch][i] (+ELU)
// L2: HEADS=1, D=128, G=16 (1024 thr, 256 blocks) -> writes out[i][ch] (+ELU)
// C/D layout (verified): col=lane&15, row=quad*4+reg.
// ---------------------------------------------------------------------------
template <int HEADS, int D, int G, int WPE>
__global__ __launch_bounds__(G * 64, WPE) void attn_fused(
        const unsigned* __restrict__ maskT,             // [N/32][N]
        const __hip_bfloat16* __restrict__ WhB,          // [H][N/32][D/16][64][8]
        const float* __restrict__ f1g, const float* __restrict__ f2g,
        float* __restrict__ outp) {
    constexpr int CT = D / 16;
    constexpr int CC = (D == 64) ? 1 : 2;    // ct-tiles per epilogue round
    constexpr int KSTEPS = N / (32 * G);
    __shared__ float sh[G * 16 * CC * 17];
    __shared__ float dsh[G * 16];
    const int t = threadIdx.x;
    const int g = t >> 6, lane = t & 63;
    const int m = lane & 15, quad = lane >> 4;
    const int h = blockIdx.y;
    const int i0 = blockIdx.x * 16;
    const int i = i0 + m;

    const float f1v = f1g[(size_t)h * N + i];
    const float* f2p = f2g + (size_t)h * N;
    const bf16x8* whb = (const bf16x8*)WhB + (size_t)h * (N / 32) * CT * 64;

    const f32x4 zero = {0.f, 0.f, 0.f, 0.f};
    f32x4 acc[CT];
    f32x4 sac = zero;
#pragma unroll
    for (int ct = 0; ct < CT; ct++) acc[ct] = zero;
    const short one_bf = (short)0x3F80;
    const bf16x8 ones = {one_bf, one_bf, one_bf, one_bf,
                         one_bf, one_bf, one_bf, one_bf};

    for (int ks = 0; ks < KSTEPS; ks++) {
        const int j0 = g * (N / G) + ks * 32;
        const int jw = j0 >> 5;
        // ---- loads first ----
        const unsigned mwrd = maskT[(size_t)jw * N + i];
        const float4 f2lo = *(const float4*)(f2p + j0 + quad * 8);
        const float4 f2hi = *(const float4*)(f2p + j0 + quad * 8 + 4);
        bf16x8 bfrag[CT];
        const bf16x8* bp = whb + (size_t)jw * CT * 64 + lane;
#pragma unroll
        for (int ct = 0; ct < CT; ct++) bfrag[ct] = bp[ct * 64];
        // ---- P-gen ----
        const float f2v[8] = {f2lo.x, f2lo.y, f2lo.z, f2lo.w,
                              f2hi.x, f2hi.y, f2hi.z, f2hi.w};
        float p[8];
#pragma unroll
        for (int e = 0; e < 8; e++) {
            const float tt = f1v + f2v[e];
            const float lr = fmaxf(tt, 0.5f * tt);        // LeakyReLU(0.5)
            const float pe = __builtin_amdgcn_exp2f(lr);  // exp(); log2e folded
            p[e] = ((mwrd >> (quad * 8 + e)) & 1u) ? pe : 0.f;
        }
        union { bf16x8 v; __hip_bfloat162 h2[4]; } u;
#pragma unroll
        for (int e2 = 0; e2 < 4; e2++)
            u.h2[e2] = __float22bfloat162_rn(
                make_float2(p[2 * e2], p[2 * e2 + 1]));
        const bf16x8 afr = u.v;
        // ---- MFMAs ----
#pragma unroll
        for (int ct = 0; ct < CT; ct++)
            acc[ct] = __builtin_amdgcn_mfma_f32_16x16x32_bf16(
                afr, bfrag[ct], acc[ct], 0, 0, 0);
        sac = __builtin_amdgcn_mfma_f32_16x16x32_bf16(afr, ones, sac, 0, 0, 0);
    }

    // ---- epilogue: LDS cross-group reduction, CC ct-tiles per round ----
#pragma unroll
    for (int rd = 0; rd < CT / CC; rd++) {
#pragma unroll
        for (int cc = 0; cc < CC; cc++) {
            const int ct = rd * CC + cc;
#pragma unroll
            for (int r = 0; r < 4; r++)
                sh[((g * 16 + quad * 4 + r) * CC + cc) * 17 + m] = acc[ct][r];
        }
        if (rd == 0 && m == 0) {
#pragma unroll
            for (int r = 0; r < 4; r++) dsh[g * 16 + quad * 4 + r] = sac[r];
        }
        __syncthreads();
        if (t < 256 * CC) {
            int row, ch;
            if (D == 64) { row = t & 15; ch = t >> 4; }
            else         { ch = t & 31; row = (t >> 5) & 15; }
            float av = 0.f, ss = 0.f;
#pragma unroll
            for (int gg = 0; gg < G; gg++) {
                av += sh[((gg * 16 + row) * CC + (ch >> 4)) * 17 + (ch & 15)];
                ss += dsh[gg * 16 + row];
            }
            float v = av / ss;
            v = (v > 0.f) ? v : (__builtin_amdgcn_exp2f(v * LOG2E) - 1.f);
            const int chg = h * D + rd * CC * 16 + ch;
            if (D == 64)
                outp[(size_t)chg * N + i0 + row] = v;        // h1T[ch][i]
            else
                outp[(size_t)(i0 + row) * D + chg] = v;      // out[i][ch]
        }
        __syncthreads();
    }
}

// ---------------------------------------------------------------------------
// gemm2: h1T[256][N] (k-major) @ W_out[256][128] -> WhB2 fragment bf16
// [j/32][ct(8)][lane][e] + fused f1b/f2b (fp32 acc, cross-wave via LDS).
// block 256: c = t&127, rh = t>>7; rows i0..i0+7.
// ---------------------------------------------------------------------------
__global__ void gemm2_kernel(const float* __restrict__ h1T,
                             const float* __restrict__ W2,
                             const float* __restrict__ a2,
                             __hip_bfloat16* __restrict__ WhB2,
                             float* __restrict__ f1, float* __restrict__ f2) {
    __shared__ float hs[8 * IN_DIM];
    __shared__ float fred[2][2][4][2];   // [rh][chalf][r][fn]
    const int t = threadIdx.x;
    const int c = t & 127, rh = t >> 7;
    const int i0 = blockIdx.x * 8;
    for (int u = t; u < 8 * IN_DIM; u += 256) {
        const int r = u & 7, k = u >> 3;
        hs[r * IN_DIM + k] = h1T[(size_t)k * N + i0 + r];
    }
    __syncthreads();
    float acc[4];
#pragma unroll
    for (int rr = 0; rr < 4; rr++) acc[rr] = 0.f;
    for (int k = 0; k < IN_DIM; k += 4) {
        const float w0 = W2[(size_t)(k + 0) * OUT_DIM + c];
        const float w1 = W2[(size_t)(k + 1) * OUT_DIM + c];
        const float w2 = W2[(size_t)(k + 2) * OUT_DIM + c];
        const float w3 = W2[(size_t)(k + 3) * OUT_DIM + c];
#pragma unroll
        for (int rr = 0; rr < 4; rr++) {
            const float4 hv = *(const float4*)(hs + (rh * 4 + rr) * IN_DIM + k);
            acc[rr] += hv.x * w0 + hv.y * w1 + hv.z * w2 + hv.w * w3;
        }
    }
    union { ushort u[4]; uint2 v; } cv;
#pragma unroll
    for (int rr = 0; rr < 4; rr++)
        cv.u[rr] = __hip_bfloat16_raw(__float2bfloat16(acc[rr])).x;
    const int jblk = i0 >> 5, quad = (i0 >> 3) & 3;
    const int lane_idx = (c & 15) + 16 * quad;
    *(uint2*)((__hip_bfloat16*)WhB2 +
              (((size_t)jblk * 8 + (c >> 4)) * 64 + lane_idx) * 8 + rh * 4) = cv.v;
    // fused f projections
    const float av1 = a2[c], av2 = a2[OUT_DIM + c];
    float s1[4], s2[4];
#pragma unroll
    for (int rr = 0; rr < 4; rr++) { s1[rr] = acc[rr] * av1; s2[rr] = acc[rr] * av2; }
#pragma unroll
    for (int mm = 32; mm > 0; mm >>= 1) {
#pragma unroll
        for (int rr = 0; rr < 4; rr++) {
            s1[rr] += __shfl_xor(s1[rr], mm, 64);
            s2[rr] += __shfl_xor(s2[rr], mm, 64);
        }
    }
    if ((t & 63) == 0) {
        const int chalf = (t >> 6) & 1;
#pragma unroll
        for (int rr = 0; rr < 4; rr++) {
            fred[rh][chalf][rr][0] = s1[rr];
            fred[rh][chalf][rr][1] = s2[rr];
        }
    }
    __syncthreads();
    if (t < 16) {
        const int fn = t & 1, rr = (t >> 1) & 3, rh2 = t >> 3;
        const float v = (fred[rh2][0][rr][fn] + fred[rh2][1][rr][fn]) * LOG2E;
        (fn ? f2 : f1)[i0 + rh2 * 4 + rr] = v;
    }
}

// ---------------------------------------------------------------------------
extern "C" void kernel_launch(void* const* d_in, const int* in_sizes, int n_in,
                              void* d_out, int out_size, void* d_ws, size_t ws_size,
                              hipStream_t stream) {
    const float* x   = (const float*)d_in[0];
    const int*   adj = (const int*)d_in[1];
    const float* Wh_ = (const float*)d_in[2];
    const float* ah  = (const float*)d_in[3];
    const float* W2  = (const float*)d_in[4];
    const float* a2  = (const float*)d_in[5];
    float* out = (float*)d_out;

    float* ws = (float*)d_ws;
    float* f1a = ws;                                    // 4*N
    float* f2a = f1a + (size_t)NHEADS * N;              // 4*N
    float* f1b = f2a + (size_t)NHEADS * N;              // N
    float* f2b = f1b + N;                               // N
    float* h1T = f2b + N;                               // 256*N fp32 (4MB)
    __hip_bfloat16* WhB1 = (__hip_bfloat16*)(h1T + (size_t)IN_DIM * N); // 2MB
    __hip_bfloat16* WhB2 = WhB1 + (size_t)NHEADS * HID * N;            // 1MB
    unsigned* maskT = (unsigned*)(WhB2 + (size_t)OUT_DIM * N);         // 2MB

    mask_kernel<<<dim3(N / 64, N / 16), 256, 0, stream>>>(adj, maskT);
    gemm1_kernel<<<N / 8, 256, 0, stream>>>(x, Wh_, ah, WhB1, f1a, f2a);
    attn_fused<NHEADS, HID, 8, 6>
        <<<dim3(N / 16, NHEADS), 512, 0, stream>>>(maskT, WhB1, f1a, f2a, h1T);
    gemm2_kernel<<<N / 8, 256, 0, stream>>>(h1T, W2, a2, WhB2, f1b, f2b);
    attn_fused<1, OUT_DIM, 16, 4>
        <<<dim3(N / 16, 1), 1024, 0, stream>>>(maskT, WhB2, f1b, f2b, out);
}

// Round 6
// 196.160 us; speedup vs baseline: 5.4667x; 1.0220x over previous
//
#include <hip/hip_runtime.h>
#include <hip/hip_bf16.h>

#define N 4096
#define IN_DIM 256
#define HID 64
#define NHEADS 4
#define OUT_DIM 128
#define LOG2E 1.44269504088896340736f

typedef __attribute__((ext_vector_type(8))) short bf16x8;
typedef __attribute__((ext_vector_type(4))) float f32x4;

// ---------------------------------------------------------------------------
// prep_kernel = gemm1 (blocks 0..511) + mask pack (blocks 512..1535), merged
// so the two independent stages run CONCURRENTLY in one dispatch.
//
// gemm1: x[N,256] @ W_heads[4][256][64] -> WhB1 (MFMA-B-fragment bf16 layout
// [h][j/32][ct(4)][lane(64)][e(8)]) + fused f1/f2 (log2e pre-scaled).
//
// mask: adj>0 -> transposed bitmask maskT[jw][i]. Per wave: 1 row, int4/lane
// (16B coalesced), 4 ballots, word assembly via bit-spread (bit k -> 4k):
//   x=(x|x<<12)&0x000F000F; x=(x|x<<6)&0x03030303; x=(x|x<<3)&0x11111111
// word_w bit b <- ballot[b&3] bit (8w + (b>>2))  ==> j = j0+32w+b  (verified).
// ---------------------------------------------------------------------------
__global__ __launch_bounds__(256, 4) void prep_kernel(
        const float* __restrict__ x, const float* __restrict__ W,
        const float* __restrict__ a, const int* __restrict__ adj,
        __hip_bfloat16* __restrict__ WhB,
        float* __restrict__ f1, float* __restrict__ f2,
        unsigned* __restrict__ maskT) {
    __shared__ float xs[8 * IN_DIM];
    const int t = threadIdx.x;
    if (blockIdx.x < 512) {
        // ---------------- gemm1 ----------------
        const int c = t & 63, h = t >> 6;
        const int i0 = blockIdx.x * 8;
        const float4* xg = (const float4*)(x + (size_t)i0 * IN_DIM);
        float4* xs4 = (float4*)xs;
        for (int u = t; u < 8 * IN_DIM / 4; u += 256) xs4[u] = xg[u];
        __syncthreads();
        float acc[8];
#pragma unroll
        for (int r = 0; r < 8; r++) acc[r] = 0.f;
        const float* Wp = W + (size_t)h * IN_DIM * HID + c;
        for (int k = 0; k < IN_DIM; k += 4) {
            const float w0 = Wp[(size_t)(k + 0) * HID];
            const float w1 = Wp[(size_t)(k + 1) * HID];
            const float w2 = Wp[(size_t)(k + 2) * HID];
            const float w3 = Wp[(size_t)(k + 3) * HID];
#pragma unroll
            for (int r = 0; r < 8; r++) {
                const float4 xv = *(const float4*)(xs + r * IN_DIM + k);
                acc[r] += xv.x * w0 + xv.y * w1 + xv.z * w2 + xv.w * w3;
            }
        }
        union { ushort u[8]; uint4 v; } cv;
#pragma unroll
        for (int r = 0; r < 8; r++)
            cv.u[r] = __hip_bfloat16_raw(__float2bfloat16(acc[r])).x;
        const int jblk = i0 >> 5, quad = (i0 >> 3) & 3;
        const int lane_idx = (c & 15) + 16 * quad;
        *(uint4*)(WhB + ((((size_t)h * (N / 32) + jblk) * 4 + (c >> 4)) * 64 +
                         lane_idx) * 8) = cv.v;
        const float av1 = a[h * 2 * HID + c];
        const float av2 = a[h * 2 * HID + HID + c];
        float s1[8], s2[8];
#pragma unroll
        for (int r = 0; r < 8; r++) { s1[r] = acc[r] * av1; s2[r] = acc[r] * av2; }
#pragma unroll
        for (int mm = 32; mm > 0; mm >>= 1) {
#pragma unroll
            for (int r = 0; r < 8; r++) {
                s1[r] += __shfl_xor(s1[r], mm, 64);
                s2[r] += __shfl_xor(s2[r], mm, 64);
            }
        }
        if (c == 0) {
#pragma unroll
            for (int r = 0; r < 8; r++) {
                f1[(size_t)h * N + i0 + r] = s1[r] * LOG2E;
                f2[(size_t)h * N + i0 + r] = s2[r] * LOG2E;
            }
        }
    } else {
        // ---------------- mask pack ----------------
        const int lane = t & 63, w = t >> 6;
        const int i = (blockIdx.x - 512) * 4 + w;      // one row per wave
        const int4* arow = (const int4*)(adj + (size_t)i * N);
        for (int jb = 0; jb < N / 256; jb++) {
            const int4 a4 = arow[jb * 64 + lane];
            unsigned long long bal[4];
            bal[0] = __ballot(a4.x > 0);
            bal[1] = __ballot(a4.y > 0);
            bal[2] = __ballot(a4.z > 0);
            bal[3] = __ballot(a4.w > 0);
            if (lane < 8) {
                unsigned word = 0;
#pragma unroll
                for (int e = 0; e < 4; e++) {
                    unsigned xv = (unsigned)(bal[e] >> (8 * lane)) & 0xFFu;
                    xv = (xv | (xv << 12)) & 0x000F000Fu;
                    xv = (xv | (xv << 6))  & 0x03030303u;
                    xv = (xv | (xv << 3))  & 0x11111111u;
                    word |= xv << e;
                }
                maskT[(size_t)(jb * 8 + lane) * N + i] = word;
            }
        }
    }
}

// ---------------------------------------------------------------------------
// Fused attention layer: P-gen (bitmask+exp2) -> MFMA -> in-block LDS
// reduction over j-groups -> softmax divide -> ELU -> final store.
// Block: G waves share MW 16-row tiles (B-frags amortized over MW tiles);
// wave g covers j range [g*N/G, (g+1)*N/G).
// L1: HEADS=4, D=64,  G=4, MW=2 -> grid (128,4), 256 thr, 2 blk/CU exact.
// L2: HEADS=1, D=128, G=16, MW=1 -> grid (256,1), 1024 thr, 1 blk/CU exact.
// C/D layout (verified): col=lane&15, row=quad*4+reg.
// ---------------------------------------------------------------------------
template <int HEADS, int D, int G, int MW, int WPE>
__global__ __launch_bounds__(G * 64, WPE) void attn_fused(
        const unsigned* __restrict__ maskT,             // [N/32][N]
        const __hip_bfloat16* __restrict__ WhB,          // [H][N/32][D/16][64][8]
        const float* __restrict__ f1g, const float* __restrict__ f2g,
        float* __restrict__ outp) {
    constexpr int CT = D / 16;
    constexpr int CC = (D == 64) ? 1 : 2;    // ct-tiles per epilogue round
    constexpr int KSTEPS = N / (32 * G);
    __shared__ float sh[MW * G * 16 * CC * 17];
    __shared__ float dsh[MW * G * 16];
    const int t = threadIdx.x;
    const int g = t >> 6, lane = t & 63;
    const int m = lane & 15, quad = lane >> 4;
    const int h = blockIdx.y;
    const int i0 = blockIdx.x * (16 * MW);

    float f1v[MW];
#pragma unroll
    for (int mw = 0; mw < MW; mw++)
        f1v[mw] = f1g[(size_t)h * N + i0 + mw * 16 + m];
    const float* f2p = f2g + (size_t)h * N;
    const bf16x8* whb = (const bf16x8*)WhB + (size_t)h * (N / 32) * CT * 64;

    const f32x4 zero = {0.f, 0.f, 0.f, 0.f};
    f32x4 acc[MW][CT];
    f32x4 sac[MW];
#pragma unroll
    for (int mw = 0; mw < MW; mw++) {
        sac[mw] = zero;
#pragma unroll
        for (int ct = 0; ct < CT; ct++) acc[mw][ct] = zero;
    }
    const short one_bf = (short)0x3F80;
    const bf16x8 ones = {one_bf, one_bf, one_bf, one_bf,
                         one_bf, one_bf, one_bf, one_bf};

    for (int ks = 0; ks < KSTEPS; ks++) {
        const int j0 = g * (N / G) + ks * 32;
        const int jw = j0 >> 5;
        // ---- loads first ----
        unsigned mwrd[MW];
#pragma unroll
        for (int mw = 0; mw < MW; mw++)
            mwrd[mw] = maskT[(size_t)jw * N + i0 + mw * 16 + m];
        const float4 f2lo = *(const float4*)(f2p + j0 + quad * 8);
        const float4 f2hi = *(const float4*)(f2p + j0 + quad * 8 + 4);
        bf16x8 bfrag[CT];
        const bf16x8* bp = whb + (size_t)jw * CT * 64 + lane;
#pragma unroll
        for (int ct = 0; ct < CT; ct++) bfrag[ct] = bp[ct * 64];
        // ---- P-gen per row-tile ----
        const float f2v[8] = {f2lo.x, f2lo.y, f2lo.z, f2lo.w,
                              f2hi.x, f2hi.y, f2hi.z, f2hi.w};
        bf16x8 afr[MW];
#pragma unroll
        for (int mw = 0; mw < MW; mw++) {
            float p[8];
#pragma unroll
            for (int e = 0; e < 8; e++) {
                const float tt = f1v[mw] + f2v[e];
                const float lr = fmaxf(tt, 0.5f * tt);        // LeakyReLU(0.5)
                const float pe = __builtin_amdgcn_exp2f(lr);  // log2e folded
                p[e] = ((mwrd[mw] >> (quad * 8 + e)) & 1u) ? pe : 0.f;
            }
            union { bf16x8 v; __hip_bfloat162 h2[4]; } u;
#pragma unroll
            for (int e2 = 0; e2 < 4; e2++)
                u.h2[e2] = __float22bfloat162_rn(
                    make_float2(p[2 * e2], p[2 * e2 + 1]));
            afr[mw] = u.v;
        }
        // ---- MFMAs (B amortized across MW row-tiles) ----
#pragma unroll
        for (int ct = 0; ct < CT; ct++)
#pragma unroll
            for (int mw = 0; mw < MW; mw++)
                acc[mw][ct] = __builtin_amdgcn_mfma_f32_16x16x32_bf16(
                    afr[mw], bfrag[ct], acc[mw][ct], 0, 0, 0);
#pragma unroll
        for (int mw = 0; mw < MW; mw++)
            sac[mw] = __builtin_amdgcn_mfma_f32_16x16x32_bf16(
                afr[mw], ones, sac[mw], 0, 0, 0);
    }

    // ---- epilogue: LDS cross-group reduction, CC ct-tiles per round ----
#pragma unroll
    for (int rd = 0; rd < CT / CC; rd++) {
#pragma unroll
        for (int mw = 0; mw < MW; mw++) {
#pragma unroll
            for (int cc = 0; cc < CC; cc++) {
#pragma unroll
                for (int r = 0; r < 4; r++)
                    sh[(((mw * G + g) * 16 + quad * 4 + r) * CC + cc) * 17 + m] =
                        acc[mw][rd * CC + cc][r];
            }
            if (rd == 0 && m == 0) {
#pragma unroll
                for (int r = 0; r < 4; r++)
                    dsh[(mw * G + g) * 16 + quad * 4 + r] = sac[mw][r];
            }
        }
        __syncthreads();
        if (t < 16 * CC * 16) {
            int row, chl;
            if (D == 64) { row = t & 15; chl = (t >> 4) & 15; }
            else         { chl = t & 31; row = (t >> 5) & 15; }
#pragma unroll
            for (int mw = 0; mw < MW; mw++) {
                float av = 0.f, ss = 0.f;
#pragma unroll
                for (int gg = 0; gg < G; gg++) {
                    av += sh[(((mw * G + gg) * 16 + row) * CC + (chl >> 4)) * 17 +
                             (chl & 15)];
                    ss += dsh[(mw * G + gg) * 16 + row];
                }
                float v = av / ss;
                v = (v > 0.f) ? v : (__builtin_amdgcn_exp2f(v * LOG2E) - 1.f);
                const int chg = h * D + rd * CC * 16 + chl;
                const int irow = i0 + mw * 16 + row;
                if (D == 64)
                    outp[(size_t)chg * N + irow] = v;        // h1T[ch][i]
                else
                    outp[(size_t)irow * D + chg] = v;        // out[i][ch]
            }
        }
        __syncthreads();
    }
}

// ---------------------------------------------------------------------------
// gemm2: h1T[256][N] (k-major) @ W_out[256][128] -> WhB2 fragment bf16
// [j/32][ct(8)][lane][e] + fused f1b/f2b (fp32 acc, cross-wave via LDS).
// ---------------------------------------------------------------------------
__global__ void gemm2_kernel(const float* __restrict__ h1T,
                             const float* __restrict__ W2,
                             const float* __restrict__ a2,
                             __hip_bfloat16* __restrict__ WhB2,
                             float* __restrict__ f1, float* __restrict__ f2) {
    __shared__ float hs[8 * IN_DIM];
    __shared__ float fred[2][2][4][2];   // [rh][chalf][r][fn]
    const int t = threadIdx.x;
    const int c = t & 127, rh = t >> 7;
    const int i0 = blockIdx.x * 8;
    for (int u = t; u < 8 * IN_DIM; u += 256) {
        const int r = u & 7, k = u >> 3;
        hs[r * IN_DIM + k] = h1T[(size_t)k * N + i0 + r];
    }
    __syncthreads();
    float acc[4];
#pragma unroll
    for (int rr = 0; rr < 4; rr++) acc[rr] = 0.f;
    for (int k = 0; k < IN_DIM; k += 4) {
        const float w0 = W2[(size_t)(k + 0) * OUT_DIM + c];
        const float w1 = W2[(size_t)(k + 1) * OUT_DIM + c];
        const float w2 = W2[(size_t)(k + 2) * OUT_DIM + c];
        const float w3 = W2[(size_t)(k + 3) * OUT_DIM + c];
#pragma unroll
        for (int rr = 0; rr < 4; rr++) {
            const float4 hv = *(const float4*)(hs + (rh * 4 + rr) * IN_DIM + k);
            acc[rr] += hv.x * w0 + hv.y * w1 + hv.z * w2 + hv.w * w3;
        }
    }
    union { ushort u[4]; uint2 v; } cv;
#pragma unroll
    for (int rr = 0; rr < 4; rr++)
        cv.u[rr] = __hip_bfloat16_raw(__float2bfloat16(acc[rr])).x;
    const int jblk = i0 >> 5, quad = (i0 >> 3) & 3;
    const int lane_idx = (c & 15) + 16 * quad;
    *(uint2*)((__hip_bfloat16*)WhB2 +
              (((size_t)jblk * 8 + (c >> 4)) * 64 + lane_idx) * 8 + rh * 4) = cv.v;
    const float av1 = a2[c], av2 = a2[OUT_DIM + c];
    float s1[4], s2[4];
#pragma unroll
    for (int rr = 0; rr < 4; rr++) { s1[rr] = acc[rr] * av1; s2[rr] = acc[rr] * av2; }
#pragma unroll
    for (int mm = 32; mm > 0; mm >>= 1) {
#pragma unroll
        for (int rr = 0; rr < 4; rr++) {
            s1[rr] += __shfl_xor(s1[rr], mm, 64);
            s2[rr] += __shfl_xor(s2[rr], mm, 64);
        }
    }
    if ((t & 63) == 0) {
        const int chalf = (t >> 6) & 1;
#pragma unroll
        for (int rr = 0; rr < 4; rr++) {
            fred[rh][chalf][rr][0] = s1[rr];
            fred[rh][chalf][rr][1] = s2[rr];
        }
    }
    __syncthreads();
    if (t < 16) {
        const int fn = t & 1, rr = (t >> 1) & 3, rh2 = t >> 3;
        const float v = (fred[rh2][0][rr][fn] + fred[rh2][1][rr][fn]) * LOG2E;
        (fn ? f2 : f1)[i0 + rh2 * 4 + rr] = v;
    }
}

// ---------------------------------------------------------------------------
extern "C" void kernel_launch(void* const* d_in, const int* in_sizes, int n_in,
                              void* d_out, int out_size, void* d_ws, size_t ws_size,
                              hipStream_t stream) {
    const float* x   = (const float*)d_in[0];
    const int*   adj = (const int*)d_in[1];
    const float* Wh_ = (const float*)d_in[2];
    const float* ah  = (const float*)d_in[3];
    const float* W2  = (const float*)d_in[4];
    const float* a2  = (const float*)d_in[5];
    float* out = (float*)d_out;

    float* ws = (float*)d_ws;
    float* f1a = ws;                                    // 4*N
    float* f2a = f1a + (size_t)NHEADS * N;              // 4*N
    float* f1b = f2a + (size_t)NHEADS * N;              // N
    float* f2b = f1b + N;                               // N
    float* h1T = f2b + N;                               // 256*N fp32 (4MB)
    __hip_bfloat16* WhB1 = (__hip_bfloat16*)(h1T + (size_t)IN_DIM * N); // 2MB
    __hip_bfloat16* WhB2 = WhB1 + (size_t)NHEADS * HID * N;            // 1MB
    unsigned* maskT = (unsigned*)(WhB2 + (size_t)OUT_DIM * N);         // 2MB

    // gemm1 (blocks 0..511) + mask pack (512..1535), concurrent
    prep_kernel<<<1536, 256, 0, stream>>>(x, Wh_, ah, adj, WhB1, f1a, f2a, maskT);
    attn_fused<NHEADS, HID, 4, 2, 4>
        <<<dim3(N / 32, NHEADS), 256, 0, stream>>>(maskT, WhB1, f1a, f2a, h1T);
    gemm2_kernel<<<N / 8, 256, 0, stream>>>(h1T, W2, a2, WhB2, f1b, f2b);
    attn_fused<1, OUT_DIM, 16, 1, 4>
        <<<dim3(N / 16, 1), 1024, 0, stream>>>(maskT, WhB2, f1b, f2b, out);
}

// Round 7
// 185.935 us; speedup vs baseline: 5.7673x; 1.0550x over previous
//
#include <hip/hip_runtime.h>
#include <hip/hip_bf16.h>

#define N 4096
#define IN_DIM 256
#define HID 64
#define NHEADS 4
#define OUT_DIM 128
#define LOG2E 1.44269504088896340736f

typedef __attribute__((ext_vector_type(8))) short bf16x8;
typedef __attribute__((ext_vector_type(4))) float f32x4;

// ---------------------------------------------------------------------------
// prep_kernel = gemm1 (blocks 0..511) + mask pack (blocks 512..1535), merged
// so the two independent stages run CONCURRENTLY in one dispatch.
// ---------------------------------------------------------------------------
__global__ __launch_bounds__(256, 4) void prep_kernel(
        const float* __restrict__ x, const float* __restrict__ W,
        const float* __restrict__ a, const int* __restrict__ adj,
        __hip_bfloat16* __restrict__ WhB,
        float* __restrict__ f1, float* __restrict__ f2,
        unsigned* __restrict__ maskT) {
    __shared__ float xs[8 * IN_DIM];
    const int t = threadIdx.x;
    if (blockIdx.x < 512) {
        // ---------------- gemm1 ----------------
        const int c = t & 63, h = t >> 6;
        const int i0 = blockIdx.x * 8;
        const float4* xg = (const float4*)(x + (size_t)i0 * IN_DIM);
        float4* xs4 = (float4*)xs;
        for (int u = t; u < 8 * IN_DIM / 4; u += 256) xs4[u] = xg[u];
        __syncthreads();
        float acc[8];
#pragma unroll
        for (int r = 0; r < 8; r++) acc[r] = 0.f;
        const float* Wp = W + (size_t)h * IN_DIM * HID + c;
        for (int k = 0; k < IN_DIM; k += 4) {
            const float w0 = Wp[(size_t)(k + 0) * HID];
            const float w1 = Wp[(size_t)(k + 1) * HID];
            const float w2 = Wp[(size_t)(k + 2) * HID];
            const float w3 = Wp[(size_t)(k + 3) * HID];
#pragma unroll
            for (int r = 0; r < 8; r++) {
                const float4 xv = *(const float4*)(xs + r * IN_DIM + k);
                acc[r] += xv.x * w0 + xv.y * w1 + xv.z * w2 + xv.w * w3;
            }
        }
        union { ushort u[8]; uint4 v; } cv;
#pragma unroll
        for (int r = 0; r < 8; r++)
            cv.u[r] = __hip_bfloat16_raw(__float2bfloat16(acc[r])).x;
        const int jblk = i0 >> 5, quad = (i0 >> 3) & 3;
        const int lane_idx = (c & 15) + 16 * quad;
        *(uint4*)(WhB + ((((size_t)h * (N / 32) + jblk) * 4 + (c >> 4)) * 64 +
                         lane_idx) * 8) = cv.v;
        const float av1 = a[h * 2 * HID + c];
        const float av2 = a[h * 2 * HID + HID + c];
        float s1[8], s2[8];
#pragma unroll
        for (int r = 0; r < 8; r++) { s1[r] = acc[r] * av1; s2[r] = acc[r] * av2; }
#pragma unroll
        for (int mm = 32; mm > 0; mm >>= 1) {
#pragma unroll
            for (int r = 0; r < 8; r++) {
                s1[r] += __shfl_xor(s1[r], mm, 64);
                s2[r] += __shfl_xor(s2[r], mm, 64);
            }
        }
        if (c == 0) {
#pragma unroll
            for (int r = 0; r < 8; r++) {
                f1[(size_t)h * N + i0 + r] = s1[r] * LOG2E;
                f2[(size_t)h * N + i0 + r] = s2[r] * LOG2E;
            }
        }
    } else {
        // ---------------- mask pack (bit-spread, verified R6) ----------------
        const int lane = t & 63, w = t >> 6;
        const int i = (blockIdx.x - 512) * 4 + w;      // one row per wave
        const int4* arow = (const int4*)(adj + (size_t)i * N);
        for (int jb = 0; jb < N / 256; jb++) {
            const int4 a4 = arow[jb * 64 + lane];
            unsigned long long bal[4];
            bal[0] = __ballot(a4.x > 0);
            bal[1] = __ballot(a4.y > 0);
            bal[2] = __ballot(a4.z > 0);
            bal[3] = __ballot(a4.w > 0);
            if (lane < 8) {
                unsigned word = 0;
#pragma unroll
                for (int e = 0; e < 4; e++) {
                    unsigned xv = (unsigned)(bal[e] >> (8 * lane)) & 0xFFu;
                    xv = (xv | (xv << 12)) & 0x000F000Fu;
                    xv = (xv | (xv << 6))  & 0x03030303u;
                    xv = (xv | (xv << 3))  & 0x11111111u;
                    word |= xv << e;
                }
                maskT[(size_t)(jb * 8 + lane) * N + i] = word;
            }
        }
    }
}

// ---------------------------------------------------------------------------
// Fused attention layer, round 7: software-pipelined K-loop (stage k+1 loads
// before compute of k), MW row-tiles amortizing B-frags, DSL channel split.
// L1: HEADS=4, DSL=1, MW=4, G=8 -> grid (64,4)=256 blocks, 512 thr, 1 blk/CU.
// L2: HEADS=1, DSL=2, MW=2, G=8 -> grid (128,2)=256 blocks, 512 thr.
// C/D layout (verified): col=lane&15, row=quad*4+reg.
// ---------------------------------------------------------------------------
template <int HEADS, int D, int DSL, int G, int MW>
__global__ __launch_bounds__(G * 64, 2) void attn_fused(
        const unsigned* __restrict__ maskT,             // [N/32][N]
        const __hip_bfloat16* __restrict__ WhB,          // [H][N/32][D/16][64][8]
        const float* __restrict__ f1g, const float* __restrict__ f2g,
        float* __restrict__ outp) {
    constexpr int CTtot = D / 16;
    constexpr int CTT = CTtot / DSL;          // ct-tiles this block owns
    constexpr int CC = (D == 64) ? 1 : 2;     // ct-tiles per epilogue round
    constexpr int KSTEPS = N / (32 * G);
    __shared__ float sh[MW * G * 16 * CC * 17];
    __shared__ float dsh[MW * G * 16];
    const int t = threadIdx.x;
    const int g = t >> 6, lane = t & 63;
    const int m = lane & 15, quad = lane >> 4;
    const int h = blockIdx.y / DSL, slc = blockIdx.y % DSL;
    const int i0 = blockIdx.x * (16 * MW);

    float f1v[MW];
#pragma unroll
    for (int mw = 0; mw < MW; mw++)
        f1v[mw] = f1g[(size_t)h * N + i0 + mw * 16 + m];
    const float* f2p = f2g + (size_t)h * N;
    const bf16x8* whb = (const bf16x8*)WhB + (size_t)h * (N / 32) * CTtot * 64;

    const f32x4 zero = {0.f, 0.f, 0.f, 0.f};
    f32x4 acc[MW][CTT];
    f32x4 sac[MW];
#pragma unroll
    for (int mw = 0; mw < MW; mw++) {
        sac[mw] = zero;
#pragma unroll
        for (int ct = 0; ct < CTT; ct++) acc[mw][ct] = zero;
    }
    const short one_bf = (short)0x3F80;
    const bf16x8 ones = {one_bf, one_bf, one_bf, one_bf,
                         one_bf, one_bf, one_bf, one_bf};

    // -------- 2-stage pipelined K-loop --------
    unsigned mwrd[2][MW];
    float f2v[2][8];
    bf16x8 bfrag[2][CTT];
    auto stage = [&](int ks, int b) {
        const int j0 = g * (N / G) + ks * 32;
        const int jw = j0 >> 5;
#pragma unroll
        for (int mw = 0; mw < MW; mw++)
            mwrd[b][mw] = maskT[(size_t)jw * N + i0 + mw * 16 + m];
        const float4 lo = *(const float4*)(f2p + j0 + quad * 8);
        const float4 hi = *(const float4*)(f2p + j0 + quad * 8 + 4);
        f2v[b][0] = lo.x; f2v[b][1] = lo.y; f2v[b][2] = lo.z; f2v[b][3] = lo.w;
        f2v[b][4] = hi.x; f2v[b][5] = hi.y; f2v[b][6] = hi.z; f2v[b][7] = hi.w;
        const bf16x8* bp = whb + ((size_t)jw * CTtot + slc * CTT) * 64 + lane;
#pragma unroll
        for (int ct = 0; ct < CTT; ct++) bfrag[b][ct] = bp[ct * 64];
    };

    stage(0, 0);
#pragma unroll 2
    for (int ks = 0; ks < KSTEPS; ks++) {
        const int cur = ks & 1;
        if (ks + 1 < KSTEPS) stage(ks + 1, cur ^ 1);
        // ---- P-gen on current stage ----
        bf16x8 afr[MW];
#pragma unroll
        for (int mw = 0; mw < MW; mw++) {
            float p[8];
#pragma unroll
            for (int e = 0; e < 8; e++) {
                const float tt = f1v[mw] + f2v[cur][e];
                const float lr = fmaxf(tt, 0.5f * tt);        // LeakyReLU(0.5)
                const float pe = __builtin_amdgcn_exp2f(lr);  // log2e folded
                p[e] = ((mwrd[cur][mw] >> (quad * 8 + e)) & 1u) ? pe : 0.f;
            }
            union { bf16x8 v; __hip_bfloat162 h2[4]; } u;
#pragma unroll
            for (int e2 = 0; e2 < 4; e2++)
                u.h2[e2] = __float22bfloat162_rn(
                    make_float2(p[2 * e2], p[2 * e2 + 1]));
            afr[mw] = u.v;
        }
        // ---- MFMAs (B amortized across MW row-tiles) ----
#pragma unroll
        for (int ct = 0; ct < CTT; ct++)
#pragma unroll
            for (int mw = 0; mw < MW; mw++)
                acc[mw][ct] = __builtin_amdgcn_mfma_f32_16x16x32_bf16(
                    afr[mw], bfrag[cur][ct], acc[mw][ct], 0, 0, 0);
#pragma unroll
        for (int mw = 0; mw < MW; mw++)
            sac[mw] = __builtin_amdgcn_mfma_f32_16x16x32_bf16(
                afr[mw], ones, sac[mw], 0, 0, 0);
    }

    // ---- epilogue: LDS cross-group reduction, CC ct-tiles per round ----
#pragma unroll
    for (int rd = 0; rd < CTT / CC; rd++) {
#pragma unroll
        for (int mw = 0; mw < MW; mw++) {
#pragma unroll
            for (int cc = 0; cc < CC; cc++) {
#pragma unroll
                for (int r = 0; r < 4; r++)
                    sh[(((mw * G + g) * 16 + quad * 4 + r) * CC + cc) * 17 + m] =
                        acc[mw][rd * CC + cc][r];
            }
            if (rd == 0 && m == 0) {
#pragma unroll
                for (int r = 0; r < 4; r++)
                    dsh[(mw * G + g) * 16 + quad * 4 + r] = sac[mw][r];
            }
        }
        __syncthreads();
        if (t < 16 * CC * 16) {
            int row, chl;
            if (D == 64) { row = t & 15; chl = (t >> 4) & 15; }
            else         { chl = t & 31; row = (t >> 5) & 15; }
#pragma unroll
            for (int mw = 0; mw < MW; mw++) {
                float av = 0.f, ss = 0.f;
#pragma unroll
                for (int gg = 0; gg < G; gg++) {
                    av += sh[(((mw * G + gg) * 16 + row) * CC + (chl >> 4)) * 17 +
                             (chl & 15)];
                    ss += dsh[(mw * G + gg) * 16 + row];
                }
                float v = av / ss;
                v = (v > 0.f) ? v : (__builtin_amdgcn_exp2f(v * LOG2E) - 1.f);
                const int chg = h * D + slc * (CTT * 16) + rd * CC * 16 + chl;
                const int irow = i0 + mw * 16 + row;
                if (D == 64)
                    outp[(size_t)chg * N + irow] = v;        // h1T[ch][i]
                else
                    outp[(size_t)irow * D + chg] = v;        // out[i][ch]
            }
        }
        __syncthreads();
    }
}

// ---------------------------------------------------------------------------
// gemm2: h1T[256][N] (k-major) @ W_out[256][128] -> WhB2 fragment bf16
// [j/32][ct(8)][lane][e] + fused f1b/f2b (fp32 acc, cross-wave via LDS).
// ---------------------------------------------------------------------------
__global__ void gemm2_kernel(const float* __restrict__ h1T,
                             const float* __restrict__ W2,
                             const float* __restrict__ a2,
                             __hip_bfloat16* __restrict__ WhB2,
                             float* __restrict__ f1, float* __restrict__ f2) {
    __shared__ float hs[8 * IN_DIM];
    __shared__ float fred[2][2][4][2];   // [rh][chalf][r][fn]
    const int t = threadIdx.x;
    const int c = t & 127, rh = t >> 7;
    const int i0 = blockIdx.x * 8;
    for (int u = t; u < 8 * IN_DIM; u += 256) {
        const int r = u & 7, k = u >> 3;
        hs[r * IN_DIM + k] = h1T[(size_t)k * N + i0 + r];
    }
    __syncthreads();
    float acc[4];
#pragma unroll
    for (int rr = 0; rr < 4; rr++) acc[rr] = 0.f;
    for (int k = 0; k < IN_DIM; k += 4) {
        const float w0 = W2[(size_t)(k + 0) * OUT_DIM + c];
        const float w1 = W2[(size_t)(k + 1) * OUT_DIM + c];
        const float w2 = W2[(size_t)(k + 2) * OUT_DIM + c];
        const float w3 = W2[(size_t)(k + 3) * OUT_DIM + c];
#pragma unroll
        for (int rr = 0; rr < 4; rr++) {
            const float4 hv = *(const float4*)(hs + (rh * 4 + rr) * IN_DIM + k);
            acc[rr] += hv.x * w0 + hv.y * w1 + hv.z * w2 + hv.w * w3;
        }
    }
    union { ushort u[4]; uint2 v; } cv;
#pragma unroll
    for (int rr = 0; rr < 4; rr++)
        cv.u[rr] = __hip_bfloat16_raw(__float2bfloat16(acc[rr])).x;
    const int jblk = i0 >> 5, quad = (i0 >> 3) & 3;
    const int lane_idx = (c & 15) + 16 * quad;
    *(uint2*)((__hip_bfloat16*)WhB2 +
              (((size_t)jblk * 8 + (c >> 4)) * 64 + lane_idx) * 8 + rh * 4) = cv.v;
    const float av1 = a2[c], av2 = a2[OUT_DIM + c];
    float s1[4], s2[4];
#pragma unroll
    for (int rr = 0; rr < 4; rr++) { s1[rr] = acc[rr] * av1; s2[rr] = acc[rr] * av2; }
#pragma unroll
    for (int mm = 32; mm > 0; mm >>= 1) {
#pragma unroll
        for (int rr = 0; rr < 4; rr++) {
            s1[rr] += __shfl_xor(s1[rr], mm, 64);
            s2[rr] += __shfl_xor(s2[rr], mm, 64);
        }
    }
    if ((t & 63) == 0) {
        const int chalf = (t >> 6) & 1;
#pragma unroll
        for (int rr = 0; rr < 4; rr++) {
            fred[rh][chalf][rr][0] = s1[rr];
            fred[rh][chalf][rr][1] = s2[rr];
        }
    }
    __syncthreads();
    if (t < 16) {
        const int fn = t & 1, rr = (t >> 1) & 3, rh2 = t >> 3;
        const float v = (fred[rh2][0][rr][fn] + fred[rh2][1][rr][fn]) * LOG2E;
        (fn ? f2 : f1)[i0 + rh2 * 4 + rr] = v;
    }
}

// ---------------------------------------------------------------------------
extern "C" void kernel_launch(void* const* d_in, const int* in_sizes, int n_in,
                              void* d_out, int out_size, void* d_ws, size_t ws_size,
                              hipStream_t stream) {
    const float* x   = (const float*)d_in[0];
    const int*   adj = (const int*)d_in[1];
    const float* Wh_ = (const float*)d_in[2];
    const float* ah  = (const float*)d_in[3];
    const float* W2  = (const float*)d_in[4];
    const float* a2  = (const float*)d_in[5];
    float* out = (float*)d_out;

    float* ws = (float*)d_ws;
    float* f1a = ws;                                    // 4*N
    float* f2a = f1a + (size_t)NHEADS * N;              // 4*N
    float* f1b = f2a + (size_t)NHEADS * N;              // N
    float* f2b = f1b + N;                               // N
    float* h1T = f2b + N;                               // 256*N fp32 (4MB)
    __hip_bfloat16* WhB1 = (__hip_bfloat16*)(h1T + (size_t)IN_DIM * N); // 2MB
    __hip_bfloat16* WhB2 = WhB1 + (size_t)NHEADS * HID * N;            // 1MB
    unsigned* maskT = (unsigned*)(WhB2 + (size_t)OUT_DIM * N);         // 2MB

    // gemm1 (blocks 0..511) + mask pack (512..1535), concurrent
    prep_kernel<<<1536, 256, 0, stream>>>(x, Wh_, ah, adj, WhB1, f1a, f2a, maskT);
    attn_fused<NHEADS, HID, 1, 8, 4>
        <<<dim3(N / 64, NHEADS), 512, 0, stream>>>(maskT, WhB1, f1a, f2a, h1T);
    gemm2_kernel<<<N / 8, 256, 0, stream>>>(h1T, W2, a2, WhB2, f1b, f2b);
    attn_fused<1, OUT_DIM, 2, 8, 2>
        <<<dim3(N / 32, 2), 512, 0, stream>>>(maskT, WhB2, f1b, f2b, out);
}